// Round 7
// baseline (90.765 us; speedup 1.0000x reference)
//
#include <hip/hip_runtime.h>
#include <hip/hip_bf16.h>

// out[b,n] = 2*x.y - ||x_b||^2 - ||y_n||^2
// x: [M=4096, K=1024] f32   y: [N=8192, K=1024] f32   out: [M, N] f32
//
// Round 7: read-ahead phases. 256x256 tile, BK=64, 8 waves, 16x16x32 MFMA.
// Each phase: {BAR; ds_reads for NEXT phase; stage 1 half; MFMA (reg-only)}.
// MFMA has no intra-phase lgkm dependency -> reads overlap MFMA issue.
// One barrier per phase. Counted vmcnt(6)@P1 / vmcnt(2)@P2, never 0 mid-loop.
// T2 swizzle (round-3 verified, conflicts=0), XCD 8x8 region swizzle, setprio.

typedef __attribute__((ext_vector_type(8)))  short bf16x8;
typedef __attribute__((ext_vector_type(4))) float f32x4;

#define BM 256
#define BN 256
#define KDIM 1024
#define NT 16                  // K-tiles of BK=64

__device__ __forceinline__ short f2bf(float f) {
    __hip_bfloat16 h = __float2bfloat16(f);
    return *reinterpret_cast<short*>(&h);
}

__device__ __forceinline__ void gld16(const short* g, short* l) {
    __builtin_amdgcn_global_load_lds(
        (const __attribute__((address_space(1))) unsigned int*)g,
        (__attribute__((address_space(3))) unsigned int*)l,
        16, 0, 0);
}

#define SBAR() __builtin_amdgcn_sched_barrier(0)
#define BAR()  do { SBAR(); asm volatile("s_barrier" ::: "memory"); } while (0)

// ---------------- prep: f32 -> bf16 + row squared-norms -------------------
__global__ __launch_bounds__(256) void prep_kernel(
    const float* __restrict__ x, const float* __restrict__ y,
    short* __restrict__ xb, short* __restrict__ yb,
    float* __restrict__ xsq, float* __restrict__ ysq, int M, int N)
{
    int row = blockIdx.x;
    const float* src;
    short* dst;
    float* nrm;
    if (row < M) {
        src = x + (size_t)row * KDIM;
        dst = xb + (size_t)row * KDIM;
        nrm = xsq + row;
    } else {
        int r = row - M;
        src = y + (size_t)r * KDIM;
        dst = yb + (size_t)r * KDIM;
        nrm = ysq + r;
    }
    int t = threadIdx.x;                       // 256 threads, 4 floats each
    float4 v = ((const float4*)src)[t];
    float s = v.x * v.x + v.y * v.y + v.z * v.z + v.w * v.w;
    short4 o;
    o.x = f2bf(v.x); o.y = f2bf(v.y); o.z = f2bf(v.z); o.w = f2bf(v.w);
    ((short4*)dst)[t] = o;

    #pragma unroll
    for (int off = 32; off > 0; off >>= 1) s += __shfl_down(s, off, 64);
    __shared__ float red[4];
    if ((t & 63) == 0) red[t >> 6] = s;
    __syncthreads();
    if (t == 0) *nrm = red[0] + red[1] + red[2] + red[3];
}

// ---------------- main 256x256 read-ahead bf16 MFMA GEMM ------------------
// LDS: A[2buf][2half][128][64] shorts (0..32767), B same (32768..65535).
__global__ __launch_bounds__(512, 2) void gemm_l2(
    const short* __restrict__ xb, const short* __restrict__ yb,
    const float* __restrict__ xsq, const float* __restrict__ ysq,
    float* __restrict__ out, int M, int N)
{
    __shared__ __align__(16) short lds[65536];   // 128 KiB

    const int ntm = M / BM;             // 16
    const int ntn = N / BN;             // 32
    const int bid = blockIdx.x;
    int tm, tn;
    if (ntm == 16 && ntn == 32) {
        int xcd = bid & 7, k = bid >> 3;            // 8x8-region XCD swizzle
        tm = (xcd >> 2) * 8 + (k >> 3);
        tn = (xcd & 3) * 8 + (k & 7);
    } else {
        tm = bid / ntn;
        tn = bid % ntn;
    }

    const int tid  = threadIdx.x;       // 512 threads = 8 waves
    const int wid  = tid >> 6;
    const int lane = tid & 63;
    const int wm   = wid >> 2;          // 0..1
    const int wn   = wid & 3;           // 0..3
    const int l15  = lane & 15;
    const int hi   = lane >> 4;         // 0..3
    const int s8   = lane & 7;

    // ---- staging (round-3 verified swizzle): dest LINEAR, global source
    // 16B-block pre-permuted: cbs = (lane&7) ^ ((lane>>3)&7). ----
    const int r8  = lane >> 3;
    const int cbs = s8 ^ (r8 & 7);
    const short* aBase = xb + (size_t)(tm * BM + wid * 16 + r8) * KDIM + cbs * 8;
    const short* bBase = yb + (size_t)(tn * BN + wid * 16 + r8) * KDIM + cbs * 8;
    const int dstBase = wid * 1024 + lane * 8;

    #define STAGE_A(kt, h) do {                                              \
        const short* g_ = aBase + (size_t)(h) * 128 * KDIM + (size_t)(kt) * 64; \
        short* d_ = &lds[((kt) & 1) * 16384 + (h) * 8192 + dstBase];         \
        gld16(g_, d_); gld16(g_ + 8 * KDIM, d_ + 512);                       \
    } while (0)
    #define STAGE_B(kt, h) do {                                              \
        const short* g_ = bBase + (size_t)(h) * 128 * KDIM + (size_t)(kt) * 64; \
        short* d_ = &lds[32768 + ((kt) & 1) * 16384 + (h) * 8192 + dstBase]; \
        gld16(g_, d_); gld16(g_ + 8 * KDIM, d_ + 512);                       \
    } while (0)

    // ---- fragment read offsets (shorts); phys block = (ks*4+hi) ^ s8 ----
    int aro[4], bro[2], xk[2];
    #pragma unroll
    for (int i = 0; i < 4; ++i) aro[i] = (wm * 64 + i * 16 + l15) * 64;
    #pragma unroll
    for (int j = 0; j < 2; ++j) bro[j] = (wn * 32 + j * 16 + l15) * 64;
    xk[0] = ((0 + hi) ^ s8) * 8;
    xk[1] = ((4 + hi) ^ s8) * 8;

    f32x4 acc[2][4][2][2] = {};     // [mq][i][nq][j]
    bf16x8 aF0[2][4], aF1[2][4];    // A half-0 / half-1 fragments [ks][i]
    bf16x8 bF0[2][2], bF1[2][2];    // B half-0 / half-1 fragments [ks][j]

    #define MFMA_Q(mq, nq, AF, BF) do {                                      \
        _Pragma("unroll") for (int ks = 0; ks < 2; ++ks)                     \
        _Pragma("unroll") for (int i = 0; i < 4; ++i)                        \
        _Pragma("unroll") for (int j = 0; j < 2; ++j)                        \
            acc[mq][i][nq][j] = __builtin_amdgcn_mfma_f32_16x16x32_bf16(     \
                AF[ks][i], BF[ks][j], acc[mq][i][nq][j], 0, 0, 0);           \
    } while (0)

    // ---- prologue: FIFO A0(0),B0(0),A1(0),B1(0),A0(1),B0(1); drain tile 0
    STAGE_A(0, 0); STAGE_B(0, 0);
    STAGE_A(0, 1); STAGE_B(0, 1);
    STAGE_A(1, 0); STAGE_B(1, 0);
    asm volatile("s_waitcnt vmcnt(4)" ::: "memory");   // tile-0 halves resident
    BAR();

    // pre-read A0(0), B0(0)
    #pragma unroll
    for (int ks = 0; ks < 2; ++ks) {
        #pragma unroll
        for (int i = 0; i < 4; ++i)
            aF0[ks][i] = *(const bf16x8*)&lds[aro[i] + xk[ks]];
        #pragma unroll
        for (int j = 0; j < 2; ++j)
            bF0[ks][j] = *(const bf16x8*)&lds[32768 + bro[j] + xk[ks]];
    }

    for (int s = 0; s < NT; ++s) {
        const int ab = (s & 1) * 16384;            // current tile base (A)
        const int nb = ((s + 1) & 1) * 16384;      // next tile base
        const bool p1 = (s + 1 < NT);
        const bool p2 = (s + 2 < NT);

        // ===== P0: MFMA q00 (aF0 x bF0); read B1(s); stage A1(s+1) =====
        #pragma unroll
        for (int ks = 0; ks < 2; ++ks)
            #pragma unroll
            for (int j = 0; j < 2; ++j)
                bF1[ks][j] = *(const bf16x8*)&lds[32768 + ab + 8192 + bro[j] + xk[ks]];
        if (p1) STAGE_A(s + 1, 1);
        __builtin_amdgcn_s_setprio(1);
        MFMA_Q(0, 0, aF0, bF0);
        __builtin_amdgcn_s_setprio(0);
        BAR();

        // ===== P1: MFMA q01 (aF0 x bF1); read A1(s); stage B1(s+1) =====
        #pragma unroll
        for (int ks = 0; ks < 2; ++ks)
            #pragma unroll
            for (int i = 0; i < 4; ++i)
                aF1[ks][i] = *(const bf16x8*)&lds[ab + 8192 + aro[i] + xk[ks]];
        if (p1) STAGE_B(s + 1, 1);
        __builtin_amdgcn_s_setprio(1);
        MFMA_Q(0, 1, aF0, bF1);
        __builtin_amdgcn_s_setprio(0);
        asm volatile("s_waitcnt vmcnt(6)" ::: "memory");   // A0(s+1) resident
        BAR();

        // ===== P2: MFMA q10 (aF1 x bF0); read A0(s+1); stage A0(s+2) =====
        if (p1) {
            #pragma unroll
            for (int ks = 0; ks < 2; ++ks)
                #pragma unroll
                for (int i = 0; i < 4; ++i)
                    aF0[ks][i] = *(const bf16x8*)&lds[nb + aro[i] + xk[ks]];
        }
        if (p2) STAGE_A(s + 2, 0);
        __builtin_amdgcn_s_setprio(1);
        MFMA_Q(1, 0, aF1, bF0);
        __builtin_amdgcn_s_setprio(0);
        if (p2) {
            asm volatile("s_waitcnt vmcnt(2)" ::: "memory"); // B0',A1',B1' resident
        } else {
            asm volatile("s_waitcnt vmcnt(0)" ::: "memory");
        }
        BAR();

        // ===== P3: MFMA q11 (aF1 x bF1); read B0(s+1); stage B0(s+2) =====
        if (p1) {
            #pragma unroll
            for (int ks = 0; ks < 2; ++ks)
                #pragma unroll
                for (int j = 0; j < 2; ++j)
                    bF0[ks][j] = *(const bf16x8*)&lds[32768 + nb + bro[j] + xk[ks]];
        }
        if (p2) STAGE_B(s + 2, 0);
        __builtin_amdgcn_s_setprio(1);
        MFMA_Q(1, 1, aF1, bF1);
        __builtin_amdgcn_s_setprio(0);
        BAR();
    }

    // ---- epilogue: out = 2*acc - xsq[row] - ysq[col] ----
    // C/D layout (16x16): col = lane&15, row = (lane>>4)*4 + reg
    #pragma unroll
    for (int mq = 0; mq < 2; ++mq)
        #pragma unroll
        for (int i = 0; i < 4; ++i) {
            int r0 = tm * BM + mq * 128 + wm * 64 + i * 16 + hi * 4;
            #pragma unroll
            for (int nq = 0; nq < 2; ++nq)
                #pragma unroll
                for (int j = 0; j < 2; ++j) {
                    int c = tn * BN + nq * 128 + wn * 32 + j * 16 + l15;
                    float ysv = ysq[c];
                    #pragma unroll
                    for (int r = 0; r < 4; ++r) {
                        int row = r0 + r;
                        out[(size_t)row * N + c] =
                            2.0f * acc[mq][i][nq][j][r] - xsq[row] - ysv;
                    }
                }
        }
}

// ---------------- fallback (only if ws too small): exact f32 --------------
__global__ __launch_bounds__(256) void fallback_l2(
    const float* __restrict__ x, const float* __restrict__ y,
    float* __restrict__ out, int M, int N)
{
    int tx = threadIdx.x & 15, ty = threadIdx.x >> 4;
    int row = blockIdx.y * 16 + ty;
    int col = blockIdx.x * 16 + tx;
    __shared__ float xs[16][17], ys[16][17];
    float s = 0.f;
    for (int k0 = 0; k0 < KDIM; k0 += 16) {
        xs[ty][tx] = x[(size_t)row * KDIM + k0 + tx];
        ys[ty][tx] = y[(size_t)(blockIdx.x * 16 + ty) * KDIM + k0 + tx];
        __syncthreads();
        #pragma unroll
        for (int kk = 0; kk < 16; ++kk) {
            float d = xs[ty][kk] - ys[tx][kk];
            s += d * d;
        }
        __syncthreads();
    }
    out[(size_t)row * N + col] = -s;
}

extern "C" void kernel_launch(void* const* d_in, const int* in_sizes, int n_in,
                              void* d_out, int out_size, void* d_ws, size_t ws_size,
                              hipStream_t stream) {
    const float* x = (const float*)d_in[0];
    const float* y = (const float*)d_in[1];
    float* out = (float*)d_out;
    const int M = in_sizes[0] / KDIM;   // 4096
    const int N = in_sizes[1] / KDIM;   // 8192

    size_t need = (size_t)(M + N) * KDIM * sizeof(short)
                + (size_t)(M + N) * sizeof(float) + 256;
    if (ws_size >= need && M % BM == 0 && N % BN == 0) {
        char* w = (char*)d_ws;
        short* xb  = (short*)w;
        short* yb  = xb + (size_t)M * KDIM;
        float* xsq = (float*)(yb + (size_t)N * KDIM);
        float* ysq = xsq + M;

        prep_kernel<<<M + N, 256, 0, stream>>>(x, y, xb, yb, xsq, ysq, M, N);
        int grid = (M / BM) * (N / BN);   // 16*32 = 512
        gemm_l2<<<grid, 512, 0, stream>>>(xb, yb, xsq, ysq, out, M, N);
    } else {
        dim3 g(N / 16, M / 16);
        fallback_l2<<<g, 256, 0, stream>>>(x, y, out, M, N);
    }
}